// Round 2
// baseline (49973.523 us; speedup 1.0000x reference)
//
#include <hip/hip_runtime.h>
#include <math.h>

#define BB 128
#define TT 512
#define FF 128
#define HH 512
#define NG 2048
#define TC 32   // timesteps per xz chunk

__global__ __launch_bounds__(256) void k_zero(float* __restrict__ p, int n) {
  int i = blockIdx.x * 256 + threadIdx.x;
  if (i < n) p[i] = 0.f;
}

// dst[(j*512 + k)*4 + g] = src[k*2048 + g*512 + j]  (gate-interleaved U)
__global__ __launch_bounds__(256) void k_rearrange(const float* __restrict__ src,
                                                   float* __restrict__ dst) {
  int e = blockIdx.x * 256 + threadIdx.x;
  int g = e & 3;
  int k = (e >> 2) & (HH - 1);
  int j = e >> 11;
  dst[e] = src[k * NG + g * HH + j];
}

// Layer-1 x-projection: xz[tl][j*4+g][b] = b1[g*H+j] + sum_f x[b][tbase+tl][f]*W1[f][g*H+j]
// block 512: b=tid&127, jl=tid>>7 (0..3); j = bx*4+jl; two t per block (by*2).
__global__ __launch_bounds__(512) void k_proj1(const float* __restrict__ x,
                                               const float* __restrict__ W,
                                               const float* __restrict__ bias,
                                               float* __restrict__ xz, int tbase) {
  int tid = threadIdx.x;
  int b = tid & 127;
  int jl = tid >> 7;
  int j = __builtin_amdgcn_readfirstlane((int)(blockIdx.x * 4 + jl));
  int t0 = blockIdx.y * 2;
  float a[2][4];
#pragma unroll
  for (int g = 0; g < 4; ++g) { float bv = bias[g * HH + j]; a[0][g] = bv; a[1][g] = bv; }
  const float* xp0 = x + (size_t)b * (TT * FF) + (size_t)(tbase + t0) * FF;
  const float* xp1 = xp0 + FF;
  for (int k4 = 0; k4 < FF / 4; ++k4) {
    float4 x0 = *(const float4*)(xp0 + k4 * 4);
    float4 x1 = *(const float4*)(xp1 + k4 * 4);
#pragma unroll
    for (int kk = 0; kk < 4; ++kk) {
      int k = k4 * 4 + kk;
      float xv0 = (&x0.x)[kk], xv1 = (&x1.x)[kk];
#pragma unroll
      for (int g = 0; g < 4; ++g) {
        float w = W[(size_t)k * NG + g * HH + j];
        a[0][g] = fmaf(xv0, w, a[0][g]);
        a[1][g] = fmaf(xv1, w, a[1][g]);
      }
    }
  }
#pragma unroll
  for (int ti = 0; ti < 2; ++ti)
#pragma unroll
    for (int g = 0; g < 4; ++g)
      xz[((size_t)(t0 + ti) * NG + j * 4 + g) * BB + b] = a[ti][g];
}

// Layer-2 x-projection from seq chunk (in[t][k][b] layout), K = 512.
__global__ __launch_bounds__(512) void k_proj2(const float* __restrict__ in,
                                               const float* __restrict__ W,
                                               const float* __restrict__ bias,
                                               float* __restrict__ xz) {
  int tid = threadIdx.x;
  int b = tid & 127;
  int jl = tid >> 7;
  int j = __builtin_amdgcn_readfirstlane((int)(blockIdx.x * 4 + jl));
  int t0 = blockIdx.y * 2;
  float a[2][4];
#pragma unroll
  for (int g = 0; g < 4; ++g) { float bv = bias[g * HH + j]; a[0][g] = bv; a[1][g] = bv; }
  const float* sp0 = in + (size_t)t0 * HH * BB + b;
  const float* sp1 = sp0 + (size_t)HH * BB;
#pragma unroll 4
  for (int k = 0; k < HH; ++k) {
    float sv0 = sp0[(size_t)k * BB];
    float sv1 = sp1[(size_t)k * BB];
#pragma unroll
    for (int g = 0; g < 4; ++g) {
      float w = W[(size_t)k * NG + g * HH + j];
      a[0][g] = fmaf(sv0, w, a[0][g]);
      a[1][g] = fmaf(sv1, w, a[1][g]);
    }
  }
#pragma unroll
  for (int ti = 0; ti < 2; ++ti)
#pragma unroll
    for (int g = 0; g < 4; ++g)
      xz[((size_t)(t0 + ti) * NG + j * 4 + g) * BB + b] = a[ti][g];
}

// Recurrent step: z = xz_t + h_in @ U; gates; update c; write h_out.
// block 1024: b=tid&127, kq=(tid>>7)&3 (k-quarter), jl=tid>>9 (0..1); j=bx*2+jl.
// 4-way split-K + LDS reduce -> 16 waves/CU (4/SIMD) for latency hiding.
__global__ __launch_bounds__(1024) void k_step2(const float* __restrict__ Uc,
                                                const float* __restrict__ xz,
                                                const float* __restrict__ h_in,
                                                float* __restrict__ h_out,
                                                float* __restrict__ cT) {
  __shared__ float red[4096];  // [jl][kq][g][b]
  int tid = threadIdx.x;
  int b = tid & 127;
  int kq = (tid >> 7) & 3;
  int jl = tid >> 9;
  int j = __builtin_amdgcn_readfirstlane((int)(blockIdx.x * 2 + jl));
  const float* __restrict__ up = Uc + (size_t)j * HH * 4;
  float a0 = 0.f, a1 = 0.f, a2 = 0.f, a3 = 0.f;
  int k0 = kq * 128;
#pragma unroll 8
  for (int kk = 0; kk < 128; ++kk) {
    int k = k0 + kk;
    float hv = h_in[(size_t)k * BB + b];
    a0 = fmaf(hv, up[k * 4 + 0], a0);
    a1 = fmaf(hv, up[k * 4 + 1], a1);
    a2 = fmaf(hv, up[k * 4 + 2], a2);
    a3 = fmaf(hv, up[k * 4 + 3], a3);
  }
  int rbase = jl * 2048 + kq * 512 + b;
  red[rbase + 0 * 128] = a0;
  red[rbase + 1 * 128] = a1;
  red[rbase + 2 * 128] = a2;
  red[rbase + 3 * 128] = a3;
  __syncthreads();
  if (kq == 0) {
#pragma unroll
    for (int q = 1; q < 4; ++q) {
      int rb = jl * 2048 + q * 512 + b;
      a0 += red[rb + 0 * 128];
      a1 += red[rb + 1 * 128];
      a2 += red[rb + 2 * 128];
      a3 += red[rb + 3 * 128];
    }
    a0 += xz[(size_t)(j * 4 + 0) * BB + b];
    a1 += xz[(size_t)(j * 4 + 1) * BB + b];
    a2 += xz[(size_t)(j * 4 + 2) * BB + b];
    a3 += xz[(size_t)(j * 4 + 3) * BB + b];
    float ig = 1.f / (1.f + __expf(-a0));
    float fg = 1.f / (1.f + __expf(-a1));
    float gg = tanhf(a2);
    float og = 1.f / (1.f + __expf(-a3));
    int idx = j * BB + b;
    float cv = fg * cT[idx] + ig * gg;
    float hn = og * tanhf(cv);
    cT[idx] = cv;
    h_out[idx] = hn;
  }
}

// logits = h2 @ Wd + bd; softmax.  h2 is [H][B] column-major.
__global__ __launch_bounds__(64) void k_dense(const float* __restrict__ h2,
                                              const float* __restrict__ Wd,
                                              const float* __restrict__ bd,
                                              float* __restrict__ out) {
  int b = blockIdx.x * 64 + threadIdx.x;
  float acc[10];
#pragma unroll
  for (int c = 0; c < 10; ++c) acc[c] = bd[c];
  for (int k = 0; k < HH; ++k) {
    float hv = h2[k * BB + b];
#pragma unroll
    for (int c = 0; c < 10; ++c) acc[c] = fmaf(hv, Wd[k * 10 + c], acc[c]);
  }
  float m = acc[0];
#pragma unroll
  for (int c = 1; c < 10; ++c) m = fmaxf(m, acc[c]);
  float s = 0.f;
#pragma unroll
  for (int c = 0; c < 10; ++c) { acc[c] = __expf(acc[c] - m); s += acc[c]; }
  float inv = 1.f / s;
#pragma unroll
  for (int c = 0; c < 10; ++c) out[b * 10 + c] = acc[c] * inv;
}

extern "C" void kernel_launch(void* const* d_in, const int* in_sizes, int n_in,
                              void* d_out, int out_size, void* d_ws, size_t ws_size,
                              hipStream_t stream) {
  const float* x  = (const float*)d_in[0];
  const float* W1 = (const float*)d_in[1];
  const float* U1 = (const float*)d_in[2];
  const float* b1 = (const float*)d_in[3];
  const float* W2 = (const float*)d_in[4];
  const float* U2 = (const float*)d_in[5];
  const float* b2 = (const float*)d_in[6];
  const float* Wd = (const float*)d_in[7];
  const float* bd = (const float*)d_in[8];
  float* out = (float*)d_out;

  float* ws  = (float*)d_ws;
  float* seq = ws;                          // [T][H][B]  33,554,432 f
  float* cT  = seq + (size_t)TT * HH * BB;  // [H][B]
  float* hA  = cT + HH * BB;                // zeroed (layer-1 h0), L2 ping
  float* hB  = hA + HH * BB;                // L2 pong
  float* Uc1 = hB + HH * BB;                // [512][512][4]
  float* Uc2 = Uc1 + (size_t)HH * NG;
  float* xz  = Uc2 + (size_t)HH * NG;       // [TC][2048][128]  8,388,608 f
  // total ~177 MB (< 182 MB proven in R1)

  k_zero<<<512, 256, 0, stream>>>(cT, 2 * HH * BB);  // cT + hA contiguous
  k_rearrange<<<(HH * NG) / 256, 256, 0, stream>>>(U1, Uc1);
  k_rearrange<<<(HH * NG) / 256, 256, 0, stream>>>(U2, Uc2);

  // layer 1
  for (int c = 0; c < TT / TC; ++c) {
    k_proj1<<<dim3(128, TC / 2), 512, 0, stream>>>(x, W1, b1, xz, c * TC);
    for (int tl = 0; tl < TC; ++tl) {
      int t = c * TC + tl;
      const float* hin = (t == 0) ? hA : (seq + (size_t)(t - 1) * HH * BB);
      k_step2<<<256, 1024, 0, stream>>>(Uc1, xz + (size_t)tl * NG * BB, hin,
                                        seq + (size_t)t * HH * BB, cT);
    }
  }
  // layer 2 (initial h,c = layer-1 final; cT carried in place)
  for (int c = 0; c < TT / TC; ++c) {
    k_proj2<<<dim3(128, TC / 2), 512, 0, stream>>>(seq + (size_t)c * TC * HH * BB,
                                                   W2, b2, xz);
    for (int tl = 0; tl < TC; ++tl) {
      int t = c * TC + tl;
      const float* hin = (t == 0) ? (seq + (size_t)(TT - 1) * HH * BB)
                                  : ((t & 1) ? hA : hB);
      float* hout = (t & 1) ? hB : hA;  // t=511 -> hB
      k_step2<<<256, 1024, 0, stream>>>(Uc2, xz + (size_t)tl * NG * BB, hin, hout, cT);
    }
  }
  k_dense<<<BB / 64, 64, 0, stream>>>(hB, Wd, bd, out);
}

// Round 3
// 27436.169 us; speedup vs baseline: 1.8214x; 1.8214x over previous
//
#include <hip/hip_runtime.h>
#include <math.h>

#define BB 128
#define TT 512
#define FF 128
#define HH 512
#define NR 2048      // gate rows (4 gates x 512 j, permuted)
#define TC 16        // timesteps per chunk = steps per rec launch
#define HB (HH*BB)   // 65536 floats per h state

// ---------------- prep kernels ----------------

__global__ __launch_bounds__(256) void k_zero(float* __restrict__ p, int n) {
  int i = blockIdx.x * 256 + threadIdx.x;
  if (i < n) p[i] = 0.f;
}

// W[k][col] (col = g*512 + q) -> Wp[k][r], r = (q>>1)*8 + (q&1)*4 + g
__global__ __launch_bounds__(256) void k_rearr_W(const float* __restrict__ src,
                                                 float* __restrict__ dst, int n) {
  int idx = blockIdx.x * 256 + threadIdx.x;
  if (idx >= n) return;
  int k = idx >> 11, col = idx & 2047;
  int q = col & 511, g = col >> 9;
  int r = (q >> 1) * 8 + (q & 1) * 4 + g;
  dst[k * NR + r] = src[idx];
}

// U[k][col] -> Ucp[jb][k][jl*4+g]  (jb = q>>1, jl = q&1)
__global__ __launch_bounds__(256) void k_rearr_U(const float* __restrict__ src,
                                                 float* __restrict__ dst) {
  int idx = blockIdx.x * 256 + threadIdx.x;   // over 512*2048
  int k = idx >> 11, col = idx & 2047;
  int q = col & 511, g = col >> 9;
  dst[(size_t)(q >> 1) * 4096 + k * 8 + (q & 1) * 4 + g] = src[idx];
}

// ---------------- projection GEMM ----------------
// Computes xz[tl][r0..r0+128][b=0..128] = in_t @ Wp + bp for one t per blockIdx.y.
// MODE 0: input = x[b][t][f] (layer 1, KD=128). MODE 1: input = seq[t][k][b] (KD=512).
template <int MODE, int KD>
__global__ __launch_bounds__(256, 4) void k_proj(const float* __restrict__ in,
                                                 const float* __restrict__ Wp,
                                                 const float* __restrict__ bp,
                                                 float* __restrict__ xz, int t0) {
  __shared__ float Wt[16 * 132];
  __shared__ float Xs[16 * 132];
  int tid = threadIdx.x;
  int r0 = blockIdx.x * 128;
  int tl = blockIdx.y;
  int ty = tid >> 4, tx = tid & 15;
  float acc[8][8];
#pragma unroll
  for (int i = 0; i < 8; ++i)
#pragma unroll
    for (int j = 0; j < 8; ++j) acc[i][j] = 0.f;

  for (int k0 = 0; k0 < KD; k0 += 16) {
    // stage W tile [16][128]
    {
      int idx = tid * 8;
      int i = idx >> 7, rr = idx & 127;
      const float* src = Wp + (size_t)(k0 + i) * NR + r0 + rr;
      float4 v0 = *(const float4*)(src);
      float4 v1 = *(const float4*)(src + 4);
      *(float4*)&Wt[i * 132 + rr] = v0;
      *(float4*)&Wt[i * 132 + rr + 4] = v1;
    }
    // stage X tile [16][128]
    if (MODE == 1) {
      int idx = tid * 8;
      int i = idx >> 7, bb = idx & 127;
      const float* src = in + (size_t)tl * HB + (size_t)(k0 + i) * BB + bb;
      float4 v0 = *(const float4*)(src);
      float4 v1 = *(const float4*)(src + 4);
      *(float4*)&Xs[i * 132 + bb] = v0;
      *(float4*)&Xs[i * 132 + bb + 4] = v1;
    } else {
      int bb = tid >> 1, half = tid & 1;
      int tg = t0 + tl;
      const float* src = in + (size_t)bb * (TT * FF) + (size_t)tg * FF + k0 + half * 8;
      float4 v0 = *(const float4*)(src);
      float4 v1 = *(const float4*)(src + 4);
#pragma unroll
      for (int q = 0; q < 4; ++q) Xs[(half * 8 + q) * 132 + bb] = (&v0.x)[q];
#pragma unroll
      for (int q = 0; q < 4; ++q) Xs[(half * 8 + 4 + q) * 132 + bb] = (&v1.x)[q];
    }
    __syncthreads();
#pragma unroll
    for (int k = 0; k < 16; ++k) {
      float4 wA = *(const float4*)&Wt[k * 132 + ty * 8];
      float4 wB = *(const float4*)&Wt[k * 132 + ty * 8 + 4];
      float4 xA = *(const float4*)&Xs[k * 132 + tx * 8];
      float4 xB = *(const float4*)&Xs[k * 132 + tx * 8 + 4];
      float w[8] = {wA.x, wA.y, wA.z, wA.w, wB.x, wB.y, wB.z, wB.w};
      float xv[8] = {xA.x, xA.y, xA.z, xA.w, xB.x, xB.y, xB.z, xB.w};
#pragma unroll
      for (int i = 0; i < 8; ++i)
#pragma unroll
        for (int j = 0; j < 8; ++j) acc[i][j] = fmaf(w[i], xv[j], acc[i][j]);
    }
    __syncthreads();
  }
#pragma unroll
  for (int i = 0; i < 8; ++i) {
    float bv = bp[r0 + ty * 8 + i];
    float* dst = xz + ((size_t)tl * NR + r0 + ty * 8 + i) * BB + tx * 8;
    float4 o0 = {acc[i][0] + bv, acc[i][1] + bv, acc[i][2] + bv, acc[i][3] + bv};
    float4 o1 = {acc[i][4] + bv, acc[i][5] + bv, acc[i][6] + bv, acc[i][7] + bv};
    *(float4*)(dst) = o0;
    *(float4*)(dst + 4) = o1;
  }
}

// ---------------- persistent recurrent kernel (TC steps, grid-synced) ----------------
// Grid MUST be 256 blocks x 1024 threads (1 block/CU, co-resident).
// Block jb owns gate rows jb*8..jb*8+7 (j = jb*2+jl). U slice (16 KB) in LDS.
// Thread: b = tid&127, kq = tid>>7 (8-way split-K over 512 k).
// h chain: hin(s) = (s==0) ? hin0 : hchain+(s-1)*HB ; hout(s) = hchain + s*HB.
__global__ __launch_bounds__(1024, 4) void k_rec(const float* __restrict__ Ucp,
                                                 const float* __restrict__ xz,
                                                 const float* __restrict__ hin0,
                                                 float* __restrict__ hchain,
                                                 float* __restrict__ cT,
                                                 int* __restrict__ ctr) {
  __shared__ float Ul[4096];
  __shared__ float red[8192];
  __shared__ float zb[1024];
  int tid = threadIdx.x;
  int b = tid & 127;
  int kq = tid >> 7;
  int jb = blockIdx.x;

  *(float4*)&Ul[tid * 4] = *(const float4*)&Ucp[(size_t)jb * 4096 + tid * 4];

  float c_reg = 0.f;
  int jl = tid >> 7;  // valid for tail threads (tid<256): jl in {0,1}
  if (tid < 256) c_reg = cT[(jb * 2 + jl) * BB + b];
  __syncthreads();

  for (int s = 0; s < TC; ++s) {
    const float* __restrict__ h = (s == 0) ? hin0 : (hchain + (size_t)(s - 1) * HB);
    float a0 = 0.f, a1 = 0.f, a2 = 0.f, a3 = 0.f;
    float a4 = 0.f, a5 = 0.f, a6 = 0.f, a7 = 0.f;
    int k0 = kq * 64;
#pragma unroll 8
    for (int kk = 0; kk < 64; ++kk) {
      int k = k0 + kk;
      float hv = h[k * BB + b];
      float4 u0 = *(const float4*)&Ul[k * 8];
      float4 u1 = *(const float4*)&Ul[k * 8 + 4];
      a0 = fmaf(hv, u0.x, a0); a1 = fmaf(hv, u0.y, a1);
      a2 = fmaf(hv, u0.z, a2); a3 = fmaf(hv, u0.w, a3);
      a4 = fmaf(hv, u1.x, a4); a5 = fmaf(hv, u1.y, a5);
      a6 = fmaf(hv, u1.z, a6); a7 = fmaf(hv, u1.w, a7);
    }
    int rb = kq * 1024 + b;
    red[rb + 0 * 128] = a0; red[rb + 1 * 128] = a1;
    red[rb + 2 * 128] = a2; red[rb + 3 * 128] = a3;
    red[rb + 4 * 128] = a4; red[rb + 5 * 128] = a5;
    red[rb + 6 * 128] = a6; red[rb + 7 * 128] = a7;
    __syncthreads();
    {
      int ig = tid >> 7;
      float z = red[ig * 128 + b];
#pragma unroll
      for (int q = 1; q < 8; ++q) z += red[q * 1024 + ig * 128 + b];
      z += xz[((size_t)s * NR + jb * 8 + ig) * BB + b];
      zb[ig * 128 + b] = z;
    }
    __syncthreads();
    if (tid < 256) {
      float z0 = zb[(jl * 4 + 0) * 128 + b];
      float z1 = zb[(jl * 4 + 1) * 128 + b];
      float z2 = zb[(jl * 4 + 2) * 128 + b];
      float z3 = zb[(jl * 4 + 3) * 128 + b];
      float igt = 1.f / (1.f + __expf(-z0));
      float fgt = 1.f / (1.f + __expf(-z1));
      float ggt = tanhf(z2);
      float ogt = 1.f / (1.f + __expf(-z3));
      c_reg = fgt * c_reg + igt * ggt;
      float hn = ogt * tanhf(c_reg);
      float* hout = hchain + (size_t)s * HB;
      __hip_atomic_store(&hout[(jb * 2 + jl) * BB + b], hn,
                         __ATOMIC_RELAXED, __HIP_MEMORY_SCOPE_AGENT);
    }
    __syncthreads();  // each wave drains its own stores before its barrier
    if (tid == 0) {
      __hip_atomic_fetch_add(ctr, 1, __ATOMIC_ACQ_REL, __HIP_MEMORY_SCOPE_AGENT);
      int tgt = 256 * (s + 1);
      while (__hip_atomic_load(ctr, __ATOMIC_ACQUIRE, __HIP_MEMORY_SCOPE_AGENT) < tgt)
        __builtin_amdgcn_s_sleep(1);
    }
    __syncthreads();
  }
  if (tid < 256) cT[(jb * 2 + jl) * BB + b] = c_reg;
}

// ---------------- dense + softmax ----------------
__global__ __launch_bounds__(64) void k_dense(const float* __restrict__ h2,
                                              const float* __restrict__ Wd,
                                              const float* __restrict__ bd,
                                              float* __restrict__ out) {
  int b = blockIdx.x * 64 + threadIdx.x;
  float acc[10];
#pragma unroll
  for (int c = 0; c < 10; ++c) acc[c] = bd[c];
  for (int k = 0; k < HH; ++k) {
    float hv = h2[k * BB + b];
#pragma unroll
    for (int c = 0; c < 10; ++c) acc[c] = fmaf(hv, Wd[k * 10 + c], acc[c]);
  }
  float m = acc[0];
#pragma unroll
  for (int c = 1; c < 10; ++c) m = fmaxf(m, acc[c]);
  float s = 0.f;
#pragma unroll
  for (int c = 0; c < 10; ++c) { acc[c] = __expf(acc[c] - m); s += acc[c]; }
  float inv = 1.f / s;
#pragma unroll
  for (int c = 0; c < 10; ++c) out[b * 10 + c] = acc[c] * inv;
}

// ---------------- host ----------------
extern "C" void kernel_launch(void* const* d_in, const int* in_sizes, int n_in,
                              void* d_out, int out_size, void* d_ws, size_t ws_size,
                              hipStream_t stream) {
  const float* x  = (const float*)d_in[0];
  const float* W1 = (const float*)d_in[1];
  const float* U1 = (const float*)d_in[2];
  const float* b1 = (const float*)d_in[3];
  const float* W2 = (const float*)d_in[4];
  const float* U2 = (const float*)d_in[5];
  const float* b2 = (const float*)d_in[6];
  const float* Wd = (const float*)d_in[7];
  const float* bd = (const float*)d_in[8];
  float* out = (float*)d_out;

  float* ws  = (float*)d_ws;
  float* seq = ws;                               // [512][512][128]  33,554,432
  float* xz  = seq + (size_t)TT * HB;            // [16][2048][128]   4,194,304
  float* Ucp = xz + (size_t)TC * NR * BB;        // [256][512][8]     1,048,576 (shared L1/L2)
  float* Wp1 = Ucp + (size_t)256 * 4096;         //   262,144
  float* Wp2 = Wp1 + (size_t)FF * NR;            // 1,048,576
  float* bp1 = Wp2 + (size_t)HH * NR;            //     2,048
  float* bp2 = bp1 + NR;                         //     2,048
  float* hR  = bp2 + NR;                         // [16][65536]       1,048,576
  float* cT  = hR + (size_t)TC * HB;             //    65,536
  int*   ctrs = (int*)(cT + HB);                 //       128 ints
  // total ~41.2M floats ~165 MB

  // prep
  k_zero<<<(HB + 255) / 256, 256, 0, stream>>>(cT, HB);
  k_zero<<<(HB + 255) / 256, 256, 0, stream>>>(hR, HB);          // hR[0] = layer-1 h0 = 0
  k_zero<<<1, 256, 0, stream>>>((float*)ctrs, 128);
  k_rearr_W<<<(FF * NR) / 256, 256, 0, stream>>>(W1, Wp1, FF * NR);
  k_rearr_W<<<(HH * NR) / 256, 256, 0, stream>>>(W2, Wp2, HH * NR);
  k_rearr_W<<<NR / 256, 256, 0, stream>>>(b1, bp1, NR);
  k_rearr_W<<<NR / 256, 256, 0, stream>>>(b2, bp2, NR);
  k_rearr_U<<<(HH * NR) / 256, 256, 0, stream>>>(U1, Ucp);

  // layer 1: h chain lives in seq[t]
  for (int c = 0; c < TT / TC; ++c) {
    int t0 = c * TC;
    k_proj<0, FF><<<dim3(NR / 128, TC), 256, 0, stream>>>(x, Wp1, bp1, xz, t0);
    const float* hin0 = (c == 0) ? hR : (seq + (size_t)(t0 - 1) * HB);
    k_rec<<<256, 1024, 0, stream>>>(Ucp, xz, hin0, seq + (size_t)t0 * HB, cT, &ctrs[c]);
  }
  // swap U buffer to layer 2
  k_rearr_U<<<(HH * NR) / 256, 256, 0, stream>>>(U2, Ucp);
  // layer 2: h chain lives in hR ring (fresh slot per step within a launch)
  for (int c = 0; c < TT / TC; ++c) {
    int t0 = c * TC;
    k_proj<1, HH><<<dim3(NR / 128, TC), 256, 0, stream>>>(seq + (size_t)t0 * HB,
                                                          Wp2, bp2, xz, t0);
    const float* hin0 = (c == 0) ? (seq + (size_t)(TT - 1) * HB)
                                 : (hR + (size_t)(TC - 1) * HB);
    k_rec<<<256, 1024, 0, stream>>>(Ucp, xz, hin0, hR, cT, &ctrs[32 + c]);
  }
  k_dense<<<BB / 64, 64, 0, stream>>>(hR + (size_t)(TC - 1) * HB, Wd, bd, out);
}